// Round 13
// baseline (874.736 us; speedup 1.0000x reference)
//
#include <hip/hip_runtime.h>
#include <hip/hip_bf16.h>

#define BSZ 128
#define NSQ 1024
#define NSTEPC 8
#define IND 768
#define HIDD 512
#define G4D 2048
#define MLPD 512
#define KXD 1280
#define NEGV -100000.0f
#define KSG 16   // K-split chunks for gates gemm (1280/16 = 80 = 5 tiles)
#define KSH 8    // K-split chunks for hproj gemm (512/8 = 64 = 4 tiles)
#define NOCT 8   // n-split for scores kernel (1024/8 = 128 n per block)
#define LOG2E 1.4426950408889634f

typedef __attribute__((ext_vector_type(4))) float f32x4;
typedef __attribute__((ext_vector_type(8))) short short8v;

__device__ __forceinline__ void split2(float4 f0, float4 f1, short8v& hi, short8v& lo) {
  float fv[8] = {f0.x, f0.y, f0.z, f0.w, f1.x, f1.y, f1.z, f1.w};
#pragma unroll
  for (int j = 0; j < 8; ++j) {
    const unsigned ub = __builtin_bit_cast(unsigned, fv[j]);
    const unsigned hb = ub & 0xFFFF0000u;
    const float lf = fv[j] - __builtin_bit_cast(float, hb);
    hi[j] = (short)(hb >> 16);
    lo[j] = (short)(__builtin_bit_cast(unsigned, lf) >> 16);
  }
}

// tanh(x) = 1 - 2/(e^{2x}+1)
__device__ __forceinline__ float tanh_fast(float x) {
  x = fminf(fmaxf(x, -15.0f), 15.0f);
  float e = __builtin_amdgcn_exp2f(x * 2.8853900817779268f);
  float r = __builtin_amdgcn_rcpf(e + 1.0f);
  return fmaf(-2.0f, r, 1.0f);
}

// ---------------- one-time: split W1c into FRAGMENT-ORDER bf16 hi/lo planes.
// wave w = row>>6 (8 m-groups of 64), frag f=(row>>4)&3, l15=row&15,
// tile t=k>>5, l4=(k>>3)&3. unit16B = ((w*24 + t)*4 + f)*64 + l4*16 + l15
__global__ __launch_bounds__(256) void k_prep_wfrag(
    const float* __restrict__ W1c,
    unsigned short* __restrict__ wfh, unsigned short* __restrict__ wfl) {
  const int c = blockIdx.x * 256 + threadIdx.x;
  if (c >= 49152) return;  // 512 rows x 96 chunks of 8 k-elements
  const int row = c / 96, wc = c - row * 96;
  const int w = row >> 6;
  const int f = (row >> 4) & 3, l15 = row & 15;
  const int t = wc >> 2, l4 = wc & 3;
  const size_t unit = (((size_t)(w * 24 + t) * 4 + f) * 64) + l4 * 16 + l15;
  const float* src = W1c + (size_t)row * IND + wc * 8;
  const float4 f0 = *(const float4*)src, f1 = *(const float4*)(src + 4);
  short8v hi, lo;
  split2(f0, f1, hi, lo);
  *(short8v*)(wfh + unit * 8) = hi;
  *(short8v*)(wfl + unit * 8) = lo;
}

// ---------------- init: mask from ctx_len, xh = [target_emb | 0], c=0, lp=0
__global__ __launch_bounds__(256) void k_init(
    const float* __restrict__ te, const int* __restrict__ cl,
    float* __restrict__ mask, float* __restrict__ xh,
    float* __restrict__ cst, float* __restrict__ lp) {
  const int b = blockIdx.x, tid = threadIdx.x;
  const int L = cl[b];
  for (int n = tid; n < NSQ; n += 256) mask[(size_t)b*NSQ + n] = (n >= L) ? NEGV : 0.0f;
  for (int d = tid; d < IND; d += 256) xh[(size_t)b*KXD + d] = te[(size_t)b*IND + d];
  for (int j = tid; j < HIDD; j += 256) {
    xh[(size_t)b*KXD + IND + j] = 0.0f;
    cst[(size_t)b*HIDD + j] = 0.0f;
  }
  if (tid == 0) lp[b] = 0.0f;
}

// ---------------- ctx GEMM, BM=512 x BN=128, 1024 thr / 16 waves (R12 verbatim)
__global__ __launch_bounds__(1024, 1) void k_ctx10(
    const float* __restrict__ ctx,
    const unsigned short* __restrict__ wfh, const unsigned short* __restrict__ wfl,
    const float* __restrict__ bias, const int* __restrict__ clen,
    float* __restrict__ cp) {
  __shared__ __align__(16) unsigned short sCh[2][4096], sCl[2][4096];  // 128r x 32k
  const int strip = blockIdx.x;          // 1024 n-strips
  const int b = strip >> 3;
  const int nbase = (strip & 7) << 7;
  if (nbase >= clen[b]) return;          // masked region: cp never read there
  const int i0 = strip << 7;
  const int tid = threadIdx.x;
  const int lane = tid & 63, wid = tid >> 6;
  const int wm = wid >> 1, wn = wid & 1;
  const int l15 = lane & 15, l4 = lane >> 4;
  const int srow = tid >> 3, sks = tid & 7;
  const int sslot = sks >> 1, shalf = sks & 1;
  const int sswz = (srow >> 1) & 3;
  const float* ssrc = ctx + (size_t)(i0 + srow) * IND + ((sslot ^ sswz) * 8 + shalf * 4);
  const int soff = srow * 32 + sslot * 8 + shalf * 4;   // shorts
  const size_t wbase = (size_t)(wm * 24) * 2048 + lane * 8;

  auto stage = [&](int t, int buf) {
    const float4 q = *(const float4*)(ssrc + t * 32);
    unsigned h01, h23, l01, l23;
    {
      const float qq[4] = {q.x, q.y, q.z, q.w};
      unsigned hh[4], ll[4];
#pragma unroll
      for (int j = 0; j < 4; ++j) {
        const unsigned ub = __builtin_bit_cast(unsigned, qq[j]);
        const unsigned hb = ub & 0xFFFF0000u;
        const float lf = qq[j] - __builtin_bit_cast(float, hb);
        hh[j] = hb >> 16;
        ll[j] = __builtin_bit_cast(unsigned, lf) >> 16;
      }
      h01 = hh[0] | (hh[1] << 16); h23 = hh[2] | (hh[3] << 16);
      l01 = ll[0] | (ll[1] << 16); l23 = ll[2] | (ll[3] << 16);
    }
    *(uint2*)&sCh[buf][soff] = make_uint2(h01, h23);
    *(uint2*)&sCl[buf][soff] = make_uint2(l01, l23);
  };

  stage(0, 0);   // prologue

  f32x4 acc[4][4] = {};  // [fm][fn]
  for (int t = 0; t < 24; ++t) {
    __syncthreads();                       // buf[t&1] ready
    const int cur = t & 1;
    short8v wh[4], wl[4];
    const size_t toff = wbase + (size_t)t * 2048;
#pragma unroll
    for (int f = 0; f < 4; ++f) {
      wh[f] = *(const short8v*)(wfh + toff + f * 512);
      wl[f] = *(const short8v*)(wfl + toff + f * 512);
    }
#pragma unroll
    for (int fn = 0; fn < 4; ++fn) {
      const int rc = wn * 64 + fn * 16 + l15;
      const int so = (l4 ^ ((rc >> 1) & 3)) << 3;
      const short8v bhv = *(const short8v*)&sCh[cur][rc * 32 + so];
      const short8v blv = *(const short8v*)&sCl[cur][rc * 32 + so];
      __builtin_amdgcn_s_setprio(1);
#pragma unroll
      for (int fm = 0; fm < 4; ++fm) {
        acc[fm][fn] = __builtin_amdgcn_mfma_f32_16x16x32_bf16(wh[fm], bhv, acc[fm][fn], 0, 0, 0);
        acc[fm][fn] = __builtin_amdgcn_mfma_f32_16x16x32_bf16(wh[fm], blv, acc[fm][fn], 0, 0, 0);
        acc[fm][fn] = __builtin_amdgcn_mfma_f32_16x16x32_bf16(wl[fm], bhv, acc[fm][fn], 0, 0, 0);
      }
      __builtin_amdgcn_s_setprio(0);
    }
    if (t + 1 < 24) stage(t + 1, cur ^ 1);   // disjoint buffer, pre-barrier safe
  }
#pragma unroll
  for (int fm = 0; fm < 4; ++fm) {
#pragma unroll
    for (int r = 0; r < 4; ++r) {
      const int m = wm * 64 + fm * 16 + l4 * 4 + r;
      const float bb = bias[m];
      float* dst = cp + (((size_t)(b * MLPD + m)) << 10) + nbase + wn * 64 + l15;
#pragma unroll
      for (int fn = 0; fn < 4; ++fn)
        dst[fn * 16] = acc[fm][fn][r] + bb;
    }
  }
}

// ---------------- K-split partial GEMM: P[kc][i][n] = sum_{k in chunk} A[i,k]*B(n,k)
__global__ __launch_bounds__(256) void k_pgemm(
    const float* __restrict__ A, int lda, int acol,
    const float* __restrict__ B0, int ldb0, int kb,
    const float* __restrict__ B1, int ldb1,
    int kTiles, int N, float* __restrict__ P) {
  __shared__ float As[16][128];
  __shared__ float Bs[16][132];
  const int n0 = blockIdx.x * 128;
  const int kc0 = blockIdx.y * kTiles * 16;
  const int tid = threadIdx.x;
  const int tn = tid & 15;   // n-group
  const int ta = tid >> 4;   // i-group
  float acc[8][8] = {};      // [ri][ni]
  for (int t = 0; t < kTiles; ++t) {
    const int k0 = kc0 + t * 16;
#pragma unroll
    for (int u = 0; u < 2; ++u) {
      const int v = tid + u * 256;
      const int r = v >> 2, kc = v & 3;
      const float4 a4 = *(const float4*)(A + (size_t)r * lda + acol + k0 + kc * 4);
      As[kc*4+0][r] = a4.x; As[kc*4+1][r] = a4.y; As[kc*4+2][r] = a4.z; As[kc*4+3][r] = a4.w;
      const float* bp = (k0 < kb) ? (B0 + (size_t)(n0 + r) * ldb0 + k0 + kc * 4)
                                  : (B1 + (size_t)(n0 + r) * ldb1 + (k0 - kb) + kc * 4);
      const float4 b4 = *(const float4*)bp;
      Bs[kc*4+0][r] = b4.x; Bs[kc*4+1][r] = b4.y; Bs[kc*4+2][r] = b4.z; Bs[kc*4+3][r] = b4.w;
    }
    __syncthreads();
#pragma unroll
    for (int kk = 0; kk < 16; ++kk) {
      float av[8], bv[8];
#pragma unroll
      for (int q = 0; q < 8; ++q) av[q] = As[kk][ta*8+q];
#pragma unroll
      for (int q = 0; q < 8; ++q) bv[q] = Bs[kk][tn*8+q];
#pragma unroll
      for (int ri = 0; ri < 8; ++ri)
#pragma unroll
        for (int ni = 0; ni < 8; ++ni)
          acc[ri][ni] = fmaf(av[ri], bv[ni], acc[ri][ni]);
    }
    __syncthreads();
  }
#pragma unroll
  for (int ri = 0; ri < 8; ++ri) {
    const int i = ta * 8 + ri;
    float* p = P + ((size_t)blockIdx.y * BSZ + i) * N + n0 + tn * 8;
    *(float4*)(p + 0) = make_float4(acc[ri][0], acc[ri][1], acc[ri][2], acc[ri][3]);
    *(float4*)(p + 4) = make_float4(acc[ri][4], acc[ri][5], acc[ri][6], acc[ri][7]);
  }
}

// ---------------- reduce gate partials + LSTM cell update (writes c, xh h-part)
__global__ __launch_bounds__(512) void k_lstm(
    const float* __restrict__ gp, const float* __restrict__ b_ih,
    const float* __restrict__ b_hh, float* __restrict__ cst, float* __restrict__ xh) {
  const int b = blockIdx.x, j = threadIdx.x;
  float g[4];
#pragma unroll
  for (int q = 0; q < 4; ++q) {
    float s = b_ih[q*HIDD + j] + b_hh[q*HIDD + j];
#pragma unroll
    for (int ks = 0; ks < KSG; ++ks) s += gp[((size_t)ks*BSZ + b)*G4D + q*HIDD + j];
    g[q] = s;
  }
  const float c_old = cst[(size_t)b*HIDD + j];
  const float ig = 1.0f / (1.0f + expf(-g[0]));
  const float fg = 1.0f / (1.0f + expf(-g[1]));
  const float gg = tanhf(g[2]);
  const float og = 1.0f / (1.0f + expf(-g[3]));
  const float cn = fg * c_old + ig * gg;
  const float hn = og * tanhf(cn);
  cst[(size_t)b*HIDD + j] = cn;
  xh[(size_t)b*KXD + IND + j] = hn;
}

// ---------------- n-split scores + partial argmax/LSE per (b, n-oct):
// block computes full 512-m score for its 128 n, then reduces to an
// 8-float record {bestv, bestn, bests, M, S}. No psc round-trip.
__global__ __launch_bounds__(256) void k_nscore(
    const float* __restrict__ cp, const float* __restrict__ hpp,
    const float* __restrict__ w2, const int* __restrict__ clen,
    const float* __restrict__ mask, const float* __restrict__ gum,
    const float* __restrict__ b2p, float* __restrict__ rec, int step) {
  const int oct = blockIdx.x, b = blockIdx.y;
  const int len = clen[b];
  const int n0blk = oct << 7;
  if (n0blk >= len) return;              // no record for fully-masked oct
  __shared__ float hs[MLPD], ws[MLPD];
  __shared__ float2 ps2[4][64];
  const int tid = threadIdx.x;
  for (int m = tid; m < MLPD; m += 256) {
    float s = 0.0f;
#pragma unroll
    for (int ks = 0; ks < KSH; ++ks) s += hpp[((size_t)ks*BSZ + b)*MLPD + m];
    hs[m] = s;
    ws[m] = w2[m];
  }
  __syncthreads();
  const int mh = tid >> 6, nc = tid & 63;
  const int n0 = n0blk + nc * 2;
  float a0 = 0.0f, a1 = 0.0f;
  {
    const float* base = cp + (((size_t)(b * MLPD + mh * 128)) << 10) + n0;
    const float* hp = &hs[mh * 128];
    const float* wp = &ws[mh * 128];
#pragma unroll 4
    for (int m = 0; m < 128; ++m) {
      const float2 c2 = *(const float2*)(base + ((size_t)m << 10));
      const float h = hp[m], w = wp[m];
      a0 = fmaf(tanh_fast(c2.x + h), w, a0);
      a1 = fmaf(tanh_fast(c2.y + h), w, a1);
    }
  }
  ps2[mh][nc] = make_float2(a0, a1);
  __syncthreads();
  if (tid >= 64) return;                 // wave 0 finishes (no more barriers)
  const float b2 = b2p[0];
  const float2 m2 = *(const float2*)(mask + (size_t)b * NSQ + n0);
  const float2 g2 = *(const float2*)(gum + ((size_t)step * BSZ + b) * NSQ + n0);
  float sc0 = ps2[0][tid].x + ps2[1][tid].x + ps2[2][tid].x + ps2[3][tid].x + b2 + m2.x;
  float sc1 = ps2[0][tid].y + ps2[1][tid].y + ps2[2][tid].y + ps2[3][tid].y + b2 + m2.y;
  const float v0 = sc0 + g2.x, v1 = sc1 + g2.y;
  float bestv; int bestn; float bests;
  if (v1 > v0) { bestv = v1; bestn = n0 + 1; bests = sc1; }
  else         { bestv = v0; bestn = n0;     bests = sc0; }
  float msc = fmaxf(sc0, sc1);
#pragma unroll
  for (int o = 1; o < 64; o <<= 1) msc = fmaxf(msc, __shfl_xor(msc, o));
  const float M = msc;                   // block max (masked n: -1e5, never max)
  float se = __builtin_amdgcn_exp2f((sc0 - M) * LOG2E)
           + __builtin_amdgcn_exp2f((sc1 - M) * LOG2E);
#pragma unroll
  for (int o = 1; o < 64; o <<= 1) se += __shfl_xor(se, o);
#pragma unroll
  for (int o = 1; o < 64; o <<= 1) {
    const float ov = __shfl_xor(bestv, o);
    const int   on = __shfl_xor(bestn, o);
    const float os = __shfl_xor(bests, o);
    if (ov > bestv || (ov == bestv && on < bestn)) { bestv = ov; bestn = on; bests = os; }
  }
  if (tid == 0) {
    float* r = rec + (size_t)(b * NOCT + oct) * 8;
    r[0] = bestv; r[1] = (float)bestn; r[2] = bests; r[3] = M; r[4] = se;
  }
}

// ---------------- pick: merge oct records (ascending, tie->lower n), LSE merge,
// lp/mask/out update, x feedback
__global__ __launch_bounds__(192) void k_pick(
    const float* __restrict__ rec, const int* __restrict__ clen,
    float* __restrict__ mask, float* __restrict__ lp,
    const float* __restrict__ ctx, float* __restrict__ xh,
    float* __restrict__ outv, int step) {
  const int b = blockIdx.x, tid = threadIdx.x;
  __shared__ int sel;
  if (tid == 0) {
    const int nv = (clen[b] + 127) >> 7;   // valid octs
    const float* r = rec + (size_t)b * NOCT * 8;
    float bv = r[0]; int bn = (int)r[1]; float bs = r[2];
    float M = r[3], S = r[4];
    for (int o = 1; o < nv; ++o) {
      const float* q = r + o * 8;
      if (q[0] > bv) { bv = q[0]; bn = (int)q[1]; bs = q[2]; }
      const float Mq = q[3];
      const float Mn = fmaxf(M, Mq);
      S = S * expf(M - Mn) + q[4] * expf(Mq - Mn);
      M = Mn;
    }
    const float nlp = lp[b] + bs - (M + logf(S));
    lp[b] = nlp;
    mask[(size_t)b * NSQ + bn] = NEGV;
    outv[step * BSZ + b] = (float)bn;
    if (step == NSTEPC - 1) outv[NSTEPC * BSZ + b] = nlp;
    sel = bn;
  }
  __syncthreads();
  const int n = sel;
  const float4* src = (const float4*)(ctx + ((size_t)b * NSQ + n) * IND);
  float4* dst = (float4*)(xh + (size_t)b * KXD);
  dst[tid] = src[tid];   // 192 threads x 16B = 768 floats
}

extern "C" void kernel_launch(void* const* d_in, const int* in_sizes, int n_in,
                              void* d_out, int out_size, void* d_ws, size_t ws_size,
                              hipStream_t stream) {
  const float* target_emb = (const float*)d_in[0];
  const float* ctx_emb   = (const float*)d_in[1];
  const int*   ctx_len   = (const int*)d_in[3];
  const float* W_ih = (const float*)d_in[5];
  const float* W_hh = (const float*)d_in[6];
  const float* b_ih = (const float*)d_in[7];
  const float* b_hh = (const float*)d_in[8];
  const float* W1c  = (const float*)d_in[9];
  const float* W1h  = (const float*)d_in[10];
  const float* b1   = (const float*)d_in[11];
  const float* w2   = (const float*)d_in[12];
  const float* b2   = (const float*)d_in[13];
  const float* gumbel = (const float*)d_in[14];
  float* out = (float*)d_out;

  float* ws = (float*)d_ws;
  size_t off = 0;
  auto alloc = [&](size_t n) { float* p = ws + off; off += (n + 63) & ~(size_t)63; return p; };

  float* cp   = alloc((size_t)BSZ * MLPD * NSQ);   // 268 MB
  float* gp   = alloc((size_t)KSG * BSZ * G4D);
  float* hpp  = alloc((size_t)KSH * BSZ * MLPD);
  float* rec  = alloc((size_t)BSZ * NOCT * 8);
  float* mask = alloc((size_t)BSZ * NSQ);
  float* xh   = alloc((size_t)BSZ * KXD);
  float* cst  = alloc((size_t)BSZ * HIDD);
  float* lp   = alloc(128);
  unsigned short* wfh = (unsigned short*)alloc(196608);   // 512x768 u16, frag-order
  unsigned short* wfl = (unsigned short*)alloc(196608);

  k_prep_wfrag<<<192, 256, 0, stream>>>(W1c, wfh, wfl);
  k_init<<<BSZ, 256, 0, stream>>>(target_emb, ctx_len, mask, xh, cst, lp);
  k_ctx10<<<1024, 1024, 0, stream>>>(ctx_emb, wfh, wfl, b1, ctx_len, cp);

  for (int t = 0; t < NSTEPC; ++t) {
    // gates partials: N=2048, K=1280 split in 16 chunks of 5 tiles
    k_pgemm<<<dim3(G4D/128, KSG), 256, 0, stream>>>(
        xh, KXD, 0, W_ih, IND, IND, W_hh, HIDD, 5, G4D, gp);
    k_lstm<<<BSZ, 512, 0, stream>>>(gp, b_ih, b_hh, cst, xh);
    // hproj partials: N=512, K=512 split in 8 chunks of 4 tiles
    k_pgemm<<<dim3(MLPD/128, KSH), 256, 0, stream>>>(
        xh, KXD, IND, W1h, HIDD, 1 << 30, nullptr, 0, 4, MLPD, hpp);
    k_nscore<<<dim3(NOCT, BSZ), 256, 0, stream>>>(
        cp, hpp, w2, ctx_len, mask, gumbel, b2, rec, t);
    k_pick<<<BSZ, 192, 0, stream>>>(rec, ctx_len, mask, lp, ctx_emb, xh, out, t);
  }
}

// Round 14
// 788.975 us; speedup vs baseline: 1.1087x; 1.1087x over previous
//
#include <hip/hip_runtime.h>
#include <hip/hip_bf16.h>

#define BSZ 128
#define NSQ 1024
#define NSTEPC 8
#define IND 768
#define HIDD 512
#define G4D 2048
#define MLPD 512
#define KXD 1280
#define NEGV -100000.0f
#define KSG 16   // K-split chunks for gates gemm (1280/16 = 80 = 5 tiles)
#define KSH 8    // K-split chunks for hproj gemm (512/8 = 64 = 4 tiles)
#define MSPLIT 4 // m-split for scores kernel

typedef __attribute__((ext_vector_type(4))) float f32x4;
typedef __attribute__((ext_vector_type(8))) short short8v;

__device__ __forceinline__ void split2(float4 f0, float4 f1, short8v& hi, short8v& lo) {
  float fv[8] = {f0.x, f0.y, f0.z, f0.w, f1.x, f1.y, f1.z, f1.w};
#pragma unroll
  for (int j = 0; j < 8; ++j) {
    const unsigned ub = __builtin_bit_cast(unsigned, fv[j]);
    const unsigned hb = ub & 0xFFFF0000u;
    const float lf = fv[j] - __builtin_bit_cast(float, hb);
    hi[j] = (short)(hb >> 16);
    lo[j] = (short)(__builtin_bit_cast(unsigned, lf) >> 16);
  }
}

// tanh(x) = 1 - 2/(e^{2x}+1)
__device__ __forceinline__ float tanh_fast(float x) {
  x = fminf(fmaxf(x, -15.0f), 15.0f);
  float e = __builtin_amdgcn_exp2f(x * 2.8853900817779268f);
  float r = __builtin_amdgcn_rcpf(e + 1.0f);
  return fmaf(-2.0f, r, 1.0f);
}

// ---------------- one-time: split W1c into FRAGMENT-ORDER bf16 hi/lo planes.
// wave w = row>>6 (8 m-groups of 64), frag f=(row>>4)&3, l15=row&15,
// tile t=k>>5, l4=(k>>3)&3. unit16B = ((w*24 + t)*4 + f)*64 + l4*16 + l15
__global__ __launch_bounds__(256) void k_prep_wfrag(
    const float* __restrict__ W1c,
    unsigned short* __restrict__ wfh, unsigned short* __restrict__ wfl) {
  const int c = blockIdx.x * 256 + threadIdx.x;
  if (c >= 49152) return;  // 512 rows x 96 chunks of 8 k-elements
  const int row = c / 96, wc = c - row * 96;
  const int w = row >> 6;
  const int f = (row >> 4) & 3, l15 = row & 15;
  const int t = wc >> 2, l4 = wc & 3;
  const size_t unit = (((size_t)(w * 24 + t) * 4 + f) * 64) + l4 * 16 + l15;
  const float* src = W1c + (size_t)row * IND + wc * 8;
  const float4 f0 = *(const float4*)src, f1 = *(const float4*)(src + 4);
  short8v hi, lo;
  split2(f0, f1, hi, lo);
  *(short8v*)(wfh + unit * 8) = hi;
  *(short8v*)(wfl + unit * 8) = lo;
}

// ---------------- init: mask from ctx_len, xh = [target_emb | 0], c=0, lp=0
__global__ __launch_bounds__(256) void k_init(
    const float* __restrict__ te, const int* __restrict__ cl,
    float* __restrict__ mask, float* __restrict__ xh,
    float* __restrict__ cst, float* __restrict__ lp) {
  const int b = blockIdx.x, tid = threadIdx.x;
  const int L = cl[b];
  for (int n = tid; n < NSQ; n += 256) mask[(size_t)b*NSQ + n] = (n >= L) ? NEGV : 0.0f;
  for (int d = tid; d < IND; d += 256) xh[(size_t)b*KXD + d] = te[(size_t)b*IND + d];
  for (int j = tid; j < HIDD; j += 256) {
    xh[(size_t)b*KXD + IND + j] = 0.0f;
    cst[(size_t)b*HIDD + j] = 0.0f;
  }
  if (tid == 0) lp[b] = 0.0f;
}

// ---------------- ctx GEMM, BM=512 x BN=128, 1024 thr / 16 waves:
// minimal bytes (ctx once/strip, W L2-hot frag-order planes) + 4 waves/SIMD.
// Wave (wm 0..7, wn 0..1) owns m-64 x n-64, acc 4x4. ctx split once into
// XOR-swizzled LDS planes (dbuf), staging spread over all 1024 threads.
__global__ __launch_bounds__(1024, 1) void k_ctx10(
    const float* __restrict__ ctx,
    const unsigned short* __restrict__ wfh, const unsigned short* __restrict__ wfl,
    const float* __restrict__ bias, const int* __restrict__ clen,
    float* __restrict__ cp) {
  __shared__ __align__(16) unsigned short sCh[2][4096], sCl[2][4096];  // 128r x 32k
  const int strip = blockIdx.x;          // 1024 n-strips
  const int b = strip >> 3;
  const int nbase = (strip & 7) << 7;
  if (nbase >= clen[b]) return;          // masked region: cp never read there
  const int i0 = strip << 7;
  const int tid = threadIdx.x;
  const int lane = tid & 63, wid = tid >> 6;
  const int wm = wid >> 1, wn = wid & 1;
  const int l15 = lane & 15, l4 = lane >> 4;
  const int srow = tid >> 3, sks = tid & 7;
  const int sslot = sks >> 1, shalf = sks & 1;
  const int sswz = (srow >> 1) & 3;
  const float* ssrc = ctx + (size_t)(i0 + srow) * IND + ((sslot ^ sswz) * 8 + shalf * 4);
  const int soff = srow * 32 + sslot * 8 + shalf * 4;   // shorts
  const size_t wbase = (size_t)(wm * 24) * 2048 + lane * 8;

  auto stage = [&](int t, int buf) {
    const float4 q = *(const float4*)(ssrc + t * 32);
    unsigned h01, h23, l01, l23;
    {
      const float qq[4] = {q.x, q.y, q.z, q.w};
      unsigned hh[4], ll[4];
#pragma unroll
      for (int j = 0; j < 4; ++j) {
        const unsigned ub = __builtin_bit_cast(unsigned, qq[j]);
        const unsigned hb = ub & 0xFFFF0000u;
        const float lf = qq[j] - __builtin_bit_cast(float, hb);
        hh[j] = hb >> 16;
        ll[j] = __builtin_bit_cast(unsigned, lf) >> 16;
      }
      h01 = hh[0] | (hh[1] << 16); h23 = hh[2] | (hh[3] << 16);
      l01 = ll[0] | (ll[1] << 16); l23 = ll[2] | (ll[3] << 16);
    }
    *(uint2*)&sCh[buf][soff] = make_uint2(h01, h23);
    *(uint2*)&sCl[buf][soff] = make_uint2(l01, l23);
  };

  stage(0, 0);   // prologue

  f32x4 acc[4][4] = {};  // [fm][fn]
  for (int t = 0; t < 24; ++t) {
    __syncthreads();                       // buf[t&1] ready
    const int cur = t & 1;
    // W frags for this tile: direct coalesced loads (L2-hot frag-order)
    short8v wh[4], wl[4];
    const size_t toff = wbase + (size_t)t * 2048;
#pragma unroll
    for (int f = 0; f < 4; ++f) {
      wh[f] = *(const short8v*)(wfh + toff + f * 512);
      wl[f] = *(const short8v*)(wfl + toff + f * 512);
    }
#pragma unroll
    for (int fn = 0; fn < 4; ++fn) {
      const int rc = wn * 64 + fn * 16 + l15;
      const int so = (l4 ^ ((rc >> 1) & 3)) << 3;
      const short8v bhv = *(const short8v*)&sCh[cur][rc * 32 + so];
      const short8v blv = *(const short8v*)&sCl[cur][rc * 32 + so];
      __builtin_amdgcn_s_setprio(1);
#pragma unroll
      for (int fm = 0; fm < 4; ++fm) {
        acc[fm][fn] = __builtin_amdgcn_mfma_f32_16x16x32_bf16(wh[fm], bhv, acc[fm][fn], 0, 0, 0);
        acc[fm][fn] = __builtin_amdgcn_mfma_f32_16x16x32_bf16(wh[fm], blv, acc[fm][fn], 0, 0, 0);
        acc[fm][fn] = __builtin_amdgcn_mfma_f32_16x16x32_bf16(wl[fm], bhv, acc[fm][fn], 0, 0, 0);
      }
      __builtin_amdgcn_s_setprio(0);
    }
    if (t + 1 < 24) stage(t + 1, cur ^ 1);   // disjoint buffer, pre-barrier safe
  }
  // epilogue: m = wm*64 + fm*16 + l4*4 + r, n = nbase + wn*64 + fn*16 + l15
#pragma unroll
  for (int fm = 0; fm < 4; ++fm) {
#pragma unroll
    for (int r = 0; r < 4; ++r) {
      const int m = wm * 64 + fm * 16 + l4 * 4 + r;
      const float bb = bias[m];
      float* dst = cp + (((size_t)(b * MLPD + m)) << 10) + nbase + wn * 64 + l15;
#pragma unroll
      for (int fn = 0; fn < 4; ++fn)
        dst[fn * 16] = acc[fm][fn][r] + bb;
    }
  }
}

// ---------------- K-split partial GEMM: P[kc][i][n] = sum_{k in chunk} A[i,k]*B(n,k)
__global__ __launch_bounds__(256) void k_pgemm(
    const float* __restrict__ A, int lda, int acol,
    const float* __restrict__ B0, int ldb0, int kb,
    const float* __restrict__ B1, int ldb1,
    int kTiles, int N, float* __restrict__ P) {
  __shared__ float As[16][128];
  __shared__ float Bs[16][132];
  const int n0 = blockIdx.x * 128;
  const int kc0 = blockIdx.y * kTiles * 16;
  const int tid = threadIdx.x;
  const int tn = tid & 15;   // n-group
  const int ta = tid >> 4;   // i-group
  float acc[8][8] = {};      // [ri][ni]
  for (int t = 0; t < kTiles; ++t) {
    const int k0 = kc0 + t * 16;
#pragma unroll
    for (int u = 0; u < 2; ++u) {
      const int v = tid + u * 256;
      const int r = v >> 2, kc = v & 3;
      const float4 a4 = *(const float4*)(A + (size_t)r * lda + acol + k0 + kc * 4);
      As[kc*4+0][r] = a4.x; As[kc*4+1][r] = a4.y; As[kc*4+2][r] = a4.z; As[kc*4+3][r] = a4.w;
      const float* bp = (k0 < kb) ? (B0 + (size_t)(n0 + r) * ldb0 + k0 + kc * 4)
                                  : (B1 + (size_t)(n0 + r) * ldb1 + (k0 - kb) + kc * 4);
      const float4 b4 = *(const float4*)bp;
      Bs[kc*4+0][r] = b4.x; Bs[kc*4+1][r] = b4.y; Bs[kc*4+2][r] = b4.z; Bs[kc*4+3][r] = b4.w;
    }
    __syncthreads();
#pragma unroll
    for (int kk = 0; kk < 16; ++kk) {
      float av[8], bv[8];
#pragma unroll
      for (int q = 0; q < 8; ++q) av[q] = As[kk][ta*8+q];
#pragma unroll
      for (int q = 0; q < 8; ++q) bv[q] = Bs[kk][tn*8+q];
#pragma unroll
      for (int ri = 0; ri < 8; ++ri)
#pragma unroll
        for (int ni = 0; ni < 8; ++ni)
          acc[ri][ni] = fmaf(av[ri], bv[ni], acc[ri][ni]);
    }
    __syncthreads();
  }
#pragma unroll
  for (int ri = 0; ri < 8; ++ri) {
    const int i = ta * 8 + ri;
    float* p = P + ((size_t)blockIdx.y * BSZ + i) * N + n0 + tn * 8;
    *(float4*)(p + 0) = make_float4(acc[ri][0], acc[ri][1], acc[ri][2], acc[ri][3]);
    *(float4*)(p + 4) = make_float4(acc[ri][4], acc[ri][5], acc[ri][6], acc[ri][7]);
  }
}

// ---------------- reduce gate partials + LSTM cell update (writes c, xh h-part)
__global__ __launch_bounds__(512) void k_lstm(
    const float* __restrict__ gp, const float* __restrict__ b_ih,
    const float* __restrict__ b_hh, float* __restrict__ cst, float* __restrict__ xh) {
  const int b = blockIdx.x, j = threadIdx.x;
  float g[4];
#pragma unroll
  for (int q = 0; q < 4; ++q) {
    float s = b_ih[q*HIDD + j] + b_hh[q*HIDD + j];
#pragma unroll
    for (int ks = 0; ks < KSG; ++ks) s += gp[((size_t)ks*BSZ + b)*G4D + q*HIDD + j];
    g[q] = s;
  }
  const float c_old = cst[(size_t)b*HIDD + j];
  const float ig = 1.0f / (1.0f + expf(-g[0]));
  const float fg = 1.0f / (1.0f + expf(-g[1]));
  const float gg = tanhf(g[2]);
  const float og = 1.0f / (1.0f + expf(-g[3]));
  const float cn = fg * c_old + ig * gg;
  const float hn = og * tanhf(cn);
  cst[(size_t)b*HIDD + j] = cn;
  xh[(size_t)b*KXD + IND + j] = hn;
}

// ---------------- scores partial: psc[b][mh][n] = sum_{m in mh-range} tanh(cp+hp)*w2
__global__ __launch_bounds__(256) void k_scores(
    const float* __restrict__ cp, const float* __restrict__ hpp,
    const float* __restrict__ w2, const int* __restrict__ clen,
    float* __restrict__ psc) {
  const int mh = blockIdx.x;  // [0,MSPLIT)
  const int b = blockIdx.y;
  const int tid = threadIdx.x;
  __shared__ float hs[128], ws[128];
  if (tid < 128) {
    const int m = mh * 128 + tid;
    float s = 0.0f;
#pragma unroll
    for (int ks = 0; ks < KSH; ++ks) s += hpp[((size_t)ks*BSZ + b)*MLPD + m];
    hs[tid] = s;
    ws[tid] = w2[m];
  }
  __syncthreads();
  const int len = clen[b];
  const int n0 = tid * 4;
  if (n0 >= len) return;
  float ax = 0, ay = 0, az = 0, aw = 0;
  const float* base = cp + ((size_t)b * MLPD + mh * 128) * NSQ + n0;
#pragma unroll 4
  for (int mm = 0; mm < 128; ++mm) {
    const float4 c4 = *(const float4*)(base + (size_t)mm * NSQ);
    const float h = hs[mm], w = ws[mm];
    ax = fmaf(tanh_fast(c4.x + h), w, ax);
    ay = fmaf(tanh_fast(c4.y + h), w, ay);
    az = fmaf(tanh_fast(c4.z + h), w, az);
    aw = fmaf(tanh_fast(c4.w + h), w, aw);
  }
  *(float4*)(psc + ((size_t)b * MSPLIT + mh) * NSQ + n0) = make_float4(ax, ay, az, aw);
}

// ---------------- argmax + LSE + lp + mask/x update (one block per batch row)
__global__ __launch_bounds__(256) void k_argmax(
    const float* __restrict__ psc, float* __restrict__ mask,
    const float* __restrict__ gum, const float* __restrict__ b2p,
    float* __restrict__ lp, const float* __restrict__ ctx,
    float* __restrict__ xh, float* __restrict__ outv, int step) {
  const int b = blockIdx.x, tid = threadIdx.x;
  __shared__ float rv[256], rs[256], rm[256];
  __shared__ int ri[256];
  __shared__ int sel;
  const float b2 = b2p[0];
  const int n0 = tid * 4;
  const float4 m4 = *(const float4*)(mask + (size_t)b * NSQ + n0);
  float sc[4] = {b2 + m4.x, b2 + m4.y, b2 + m4.z, b2 + m4.w};
#pragma unroll
  for (int mh = 0; mh < MSPLIT; ++mh) {
    const float4 p4 = *(const float4*)(psc + ((size_t)b * MSPLIT + mh) * NSQ + n0);
    sc[0] += p4.x; sc[1] += p4.y; sc[2] += p4.z; sc[3] += p4.w;
  }
  const float4 g4 = *(const float4*)(gum + ((size_t)step * BSZ + b) * NSQ + n0);
  const float gv[4] = {g4.x, g4.y, g4.z, g4.w};
  float bestv = -1e30f, bests = 0.0f, msc = -1e30f;
  int bestn = 0;
#pragma unroll
  for (int q = 0; q < 4; ++q) {
    const float v = sc[q] + gv[q];
    if (v > bestv) { bestv = v; bestn = n0 + q; bests = sc[q]; }
    msc = fmaxf(msc, sc[q]);
  }
  rv[tid] = bestv; ri[tid] = bestn; rs[tid] = bests; rm[tid] = msc;
  __syncthreads();
  for (int o = 128; o > 0; o >>= 1) {
    if (tid < o) {
      if (rv[tid+o] > rv[tid] || (rv[tid+o] == rv[tid] && ri[tid+o] < ri[tid])) {
        rv[tid] = rv[tid+o]; ri[tid] = ri[tid+o]; rs[tid] = rs[tid+o];
      }
      rm[tid] = fmaxf(rm[tid], rm[tid+o]);
    }
    __syncthreads();
  }
  const float M = rm[0];
  __syncthreads();
  float se = 0.0f;
#pragma unroll
  for (int q = 0; q < 4; ++q)
    se += __builtin_amdgcn_exp2f((sc[q] - M) * 1.4426950408889634f);
  rm[tid] = se;
  __syncthreads();
  for (int o = 128; o > 0; o >>= 1) {
    if (tid < o) rm[tid] += rm[tid+o];
    __syncthreads();
  }
  if (tid == 0) {
    const int n = ri[0];
    const float lse = M + logf(rm[0]);
    const float nlp = lp[b] + rs[0] - lse;
    lp[b] = nlp;
    mask[(size_t)b * NSQ + n] = NEGV;
    outv[step * BSZ + b] = (float)n;
    if (step == NSTEPC - 1) outv[NSTEPC * BSZ + b] = nlp;
    sel = n;
  }
  __syncthreads();
  const int n = sel;
  const float4* src = (const float4*)(ctx + ((size_t)b * NSQ + n) * IND);
  float4* dst = (float4*)(xh + (size_t)b * KXD);
  for (int d = tid; d < IND / 4; d += 256) dst[d] = src[d];
}

extern "C" void kernel_launch(void* const* d_in, const int* in_sizes, int n_in,
                              void* d_out, int out_size, void* d_ws, size_t ws_size,
                              hipStream_t stream) {
  const float* target_emb = (const float*)d_in[0];
  const float* ctx_emb   = (const float*)d_in[1];
  const int*   ctx_len   = (const int*)d_in[3];
  const float* W_ih = (const float*)d_in[5];
  const float* W_hh = (const float*)d_in[6];
  const float* b_ih = (const float*)d_in[7];
  const float* b_hh = (const float*)d_in[8];
  const float* W1c  = (const float*)d_in[9];
  const float* W1h  = (const float*)d_in[10];
  const float* b1   = (const float*)d_in[11];
  const float* w2   = (const float*)d_in[12];
  const float* b2   = (const float*)d_in[13];
  const float* gumbel = (const float*)d_in[14];
  float* out = (float*)d_out;

  float* ws = (float*)d_ws;
  size_t off = 0;
  auto alloc = [&](size_t n) { float* p = ws + off; off += (n + 63) & ~(size_t)63; return p; };

  float* cp   = alloc((size_t)BSZ * MLPD * NSQ);   // 268 MB
  float* gp   = alloc((size_t)KSG * BSZ * G4D);
  float* hpp  = alloc((size_t)KSH * BSZ * MLPD);
  float* psc  = alloc((size_t)BSZ * MSPLIT * NSQ);
  float* mask = alloc((size_t)BSZ * NSQ);
  float* xh   = alloc((size_t)BSZ * KXD);
  float* cst  = alloc((size_t)BSZ * HIDD);
  float* lp   = alloc(128);
  unsigned short* wfh = (unsigned short*)alloc(196608);   // 512x768 u16, frag-order
  unsigned short* wfl = (unsigned short*)alloc(196608);

  k_prep_wfrag<<<192, 256, 0, stream>>>(W1c, wfh, wfl);
  k_init<<<BSZ, 256, 0, stream>>>(target_emb, ctx_len, mask, xh, cst, lp);
  k_ctx10<<<1024, 1024, 0, stream>>>(ctx_emb, wfh, wfl, b1, ctx_len, cp);

  for (int t = 0; t < NSTEPC; ++t) {
    // gates partials: N=2048, K=1280 split in 16 chunks of 5 tiles
    k_pgemm<<<dim3(G4D/128, KSG), 256, 0, stream>>>(
        xh, KXD, 0, W_ih, IND, IND, W_hh, HIDD, 5, G4D, gp);
    k_lstm<<<BSZ, 512, 0, stream>>>(gp, b_ih, b_hh, cst, xh);
    // hproj partials: N=512, K=512 split in 8 chunks of 4 tiles
    k_pgemm<<<dim3(MLPD/128, KSH), 256, 0, stream>>>(
        xh, KXD, IND, W1h, HIDD, 1 << 30, nullptr, 0, 4, MLPD, hpp);
    k_scores<<<dim3(MSPLIT, BSZ), 256, 0, stream>>>(cp, hpp, w2, ctx_len, psc);
    k_argmax<<<BSZ, 256, 0, stream>>>(psc, mask, gumbel, b2, lp, ctx_emb, xh, out, t);
  }
}